// Round 1
// 345.674 us; speedup vs baseline: 1.0977x; 1.0977x over previous
//
#include <hip/hip_runtime.h>
#include <math.h>

#define B_ 8
#define C_ 64
#define H_ 128
#define W_ 128
#define O_ 64
#define HW_ (H_ * W_)
#define OMS 29     // floats per om row (odd stride -> conflict-free b32)

typedef short    short8v __attribute__((ext_vector_type(8)));
typedef _Float16 half8v  __attribute__((ext_vector_type(8)));
typedef __fp16   fp16x2  __attribute__((ext_vector_type(2)));
typedef float    f32x4   __attribute__((ext_vector_type(4)));
typedef float    f32x16  __attribute__((ext_vector_type(16)));
typedef unsigned uint4v  __attribute__((ext_vector_type(4)));

// XOR-granule swizzle: row of 64 halfs = 8 granules of 16B; physical granule = logical ^ (row&7).
// Conflict-free for b128 reads/writes (lanes 0..7 cover all 32 banks), keeps 16B alignment.
__device__ __forceinline__ int swz(int row, int col) {
    return (row << 6) + ((((col >> 3) ^ (row & 7)) << 3)) + (col & 7);
}

__device__ __forceinline__ unsigned pack_bf16_pair(unsigned u0, unsigned u1) {
    return (u1 & 0xffff0000u) | (u0 >> 16);
}
__device__ __forceinline__ void split_rtne(float v, short* hi, short* lo) {
    unsigned u = __float_as_uint(v);
    unsigned r = (u + 0x7fffu + ((u >> 16) & 1u)) & 0xffff0000u;
    *hi = (short)(r >> 16);
    float rem = v - __uint_as_float(r);
    unsigned u2 = __float_as_uint(rem);
    unsigned r2 = (u2 + 0x7fffu + ((u2 >> 16) & 1u));
    *lo = (short)(r2 >> 16);
}

// ws: Wch[64*576] f16 ([o][k*64+c]), Womhi/Womlo[32*576] bf16 ([n][tap*64+c])
__global__ void prep_weights(const float* __restrict__ wc,
                             const float* __restrict__ wo,
                             const float* __restrict__ wm,
                             _Float16* __restrict__ Wch,
                             short* __restrict__ Womhi, short* __restrict__ Womlo)
{
    int tid = blockIdx.x * blockDim.x + threadIdx.x;
    if (tid < 64 * 576) {
        int o = tid / 576, ck = tid % 576;
        int k = ck >> 6, c = ck & 63;
        Wch[tid] = (_Float16)wc[(o * 64 + c) * 9 + k];
    }
    if (tid < 32 * 576) {
        int n = tid / 576, tk = tid % 576;
        int tap = tk >> 6, c = tk & 63;
        float v = 0.f;
        if (n < 18)      v = wo[(n * 64 + c) * 9 + tap];
        else if (n < 27) v = wm[((n - 18) * 64 + c) * 9 + tap];
        split_rtne(v, &Womhi[tid], &Womlo[tid]);
    }
}

// NCHW f32 -> NHWC f32. Each bilinear corner in the main kernel then reads
// 16 contiguous channels = one 64B cacheline = 4x dwordx4 (vs 16 strided dwords).
// b = blk&7 matches the main kernel's XCD pinning, so the producing XCD's L2
// holds the slice its consumer blocks will read.
__global__ __launch_bounds__(256) void transpose_x(const float* __restrict__ x,
                                                   float* __restrict__ xT)
{
    __shared__ float tile[64][65];
    const int t = threadIdx.x;
    const int b = blockIdx.x & 7;
    const int tp = blockIdx.x >> 3;        // 0..255: 64-pixel tile within HW
    const int lane = t & 63, wv = t >> 6;
    const float* xb = x + (size_t)b * C_ * HW_;
    const int p0 = tp * 64;
#pragma unroll
    for (int j = 0; j < 16; ++j) {
        int c = wv * 16 + j;
        tile[c][lane] = xb[(size_t)c * HW_ + p0 + lane];   // 256B coalesced
    }
    __syncthreads();
    float* ob = xT + ((size_t)b * HW_ + p0) * 64;
#pragma unroll
    for (int r = 0; r < 4; ++r) {
        int p = (t >> 4) + r * 16;
        int c4 = (t & 15) << 2;
        f32x4 v = {tile[c4][p], tile[c4 + 1][p], tile[c4 + 2][p], tile[c4 + 3][p]};
        *(f32x4*)&ob[(size_t)p * 64 + c4] = v;             // 1KB contiguous per wave
    }
}

__global__ __launch_bounds__(256, 4) void deform_mfma(
    const float* __restrict__ xT,          // NHWC: [b][y][x][c]
    const _Float16* __restrict__ Wch,
    const short* __restrict__ Womhi, const short* __restrict__ Womlo,
    float* __restrict__ out)
{
    __shared__ _Float16 sb[2][64 * 64];   // phase A: [0]=hi,[1]=lo; phase B: double buffer (16 KB)
    __shared__ float omb[64 * OMS];

    const int t = threadIdx.x;
    const int lane = t & 63;
    const int wv = t >> 6;
    const int px = lane;
    const int g = __builtin_amdgcn_readfirstlane(wv);

    const int blk = blockIdx.x;
    const int b = blk & 7;                 // XCD-batch swizzle: batch pinned to XCD (R5: FETCH 860->17 MB)
    const int rest = blk >> 3;
    const int wcol0 = (rest & 1) << 6;
    const int h = rest >> 1;
    const float* xTb = xT + (size_t)b * HW_ * 64;
    const int gc = g << 4;                 // wave-uniform channel base within NHWC pixel
    const int wcol = wcol0 + px;

    // ================= phase A: offset/mask conv via MFMA (bf16x3) =========
    f32x4 cv0 = {}, cv1 = {};
    f32x4 av4[4];
    float okn;
    {
        int yy = h - 1, xx = wcol - 1;
        okn = (((unsigned)yy < (unsigned)H_) && ((unsigned)xx < (unsigned)W_)) ? 1.f : 0.f;
        int yyc = min(max(yy, 0), H_ - 1), xxc = min(max(xx, 0), W_ - 1);
        const float* p = xTb + ((size_t)(yyc * W_ + xxc) << 6) + gc;
#pragma unroll
        for (int j = 0; j < 4; ++j) av4[j] = *(const f32x4*)(p + 4 * j);
    }
    const int mrowA = (wv << 4) + (lane & 15);
    const int kqA = (lane >> 4) << 3;
    const int n0 = lane & 15;

#pragma unroll 1
    for (int tap = 0; tap < 9; ++tap) {
        const float okc = okn;
#pragma unroll
        for (int i = 0; i < 4; ++i) {
            float s0 = av4[i][0] * okc, s1 = av4[i][1] * okc;
            float s2 = av4[i][2] * okc, s3 = av4[i][3] * okc;
            unsigned u0 = __float_as_uint(s0), u1 = __float_as_uint(s1);
            unsigned u2 = __float_as_uint(s2), u3 = __float_as_uint(s3);
            uint2 hv, lv;
            hv.x = pack_bf16_pair(u0, u1);
            hv.y = pack_bf16_pair(u2, u3);
            lv.x = pack_bf16_pair(__float_as_uint(s0 - __uint_as_float(u0 & 0xffff0000u)),
                                  __float_as_uint(s1 - __uint_as_float(u1 & 0xffff0000u)));
            lv.y = pack_bf16_pair(__float_as_uint(s2 - __uint_as_float(u2 & 0xffff0000u)),
                                  __float_as_uint(s3 - __uint_as_float(u3 & 0xffff0000u)));
            const int off = swz(px, (g << 4) + (i << 2));
            *(uint2*)&sb[0][off] = hv;
            *(uint2*)&sb[1][off] = lv;
        }
        if (tap < 8) {   // prefetch next tap's loads; fly across barrier
            int tn = tap + 1, ty = tn / 3, tx = tn - ty * 3;
            int yy = h + ty - 1, xx = wcol + tx - 1;
            okn = (((unsigned)yy < (unsigned)H_) && ((unsigned)xx < (unsigned)W_)) ? 1.f : 0.f;
            int yyc = min(max(yy, 0), H_ - 1), xxc = min(max(xx, 0), W_ - 1);
            const float* p = xTb + ((size_t)(yyc * W_ + xxc) << 6) + gc;
#pragma unroll
            for (int j = 0; j < 4; ++j) av4[j] = *(const f32x4*)(p + 4 * j);
        }
        __builtin_amdgcn_s_waitcnt(0xC07F);   // lgkmcnt(0) only — vm loads stay in flight
        __builtin_amdgcn_s_barrier();
#pragma unroll
        for (int s = 0; s < 2; ++s) {
            const int koff = (s << 5) + kqA;
            short8v ahi = *(const short8v*)&sb[0][swz(mrowA, koff)];
            short8v alo = *(const short8v*)&sb[1][swz(mrowA, koff)];
            const int kg = tap * 64 + koff;
            short8v bh0 = *(const short8v*)&Womhi[n0 * 576 + kg];
            short8v bl0 = *(const short8v*)&Womlo[n0 * 576 + kg];
            short8v bh1 = *(const short8v*)&Womhi[(n0 + 16) * 576 + kg];
            short8v bl1 = *(const short8v*)&Womlo[(n0 + 16) * 576 + kg];
            cv0 = __builtin_amdgcn_mfma_f32_16x16x32_bf16(ahi, bh0, cv0, 0, 0, 0);
            cv0 = __builtin_amdgcn_mfma_f32_16x16x32_bf16(ahi, bl0, cv0, 0, 0, 0);
            cv0 = __builtin_amdgcn_mfma_f32_16x16x32_bf16(alo, bh0, cv0, 0, 0, 0);
            cv1 = __builtin_amdgcn_mfma_f32_16x16x32_bf16(ahi, bh1, cv1, 0, 0, 0);
            cv1 = __builtin_amdgcn_mfma_f32_16x16x32_bf16(ahi, bl1, cv1, 0, 0, 0);
            cv1 = __builtin_amdgcn_mfma_f32_16x16x32_bf16(alo, bh1, cv1, 0, 0, 0);
        }
        __builtin_amdgcn_s_barrier();   // reads consumed (lgkm drained before MFMA use) -> safe rewrite
    }

    // scatter om (C-layout: col=lane&15 -> j, row=(lane>>4)*4+r -> px-within-16)
    {
        const int j0 = lane & 15;
        const int pxo = (wv << 4) + ((lane >> 4) << 2);
#pragma unroll
        for (int r = 0; r < 4; ++r) {
            omb[(pxo + r) * OMS + j0] = cv0[r];
            if (j0 < 13) omb[(pxo + r) * OMS + j0 + 16] = cv1[r];
        }
    }
    __builtin_amdgcn_s_waitcnt(0xC07F);
    __builtin_amdgcn_s_barrier();

    // ================= phase B: sampling + einsum (fp16 MFMA, pipelined) ====
    f32x16 acc = {};
    const int mhalf = wv & 1, nhalf = wv >> 1;
    const int mrow = (mhalf << 5) + (lane & 31);
    const int nrow = (nhalf << 5) + (lane & 31);
    const int kq2 = (lane >> 5) << 3;

    unsigned pnl[8];   // packed fp16 samples for the upcoming tap (8 regs)

    auto sample_tap = [&](int k) {
        const float offy = omb[px * OMS + 2 * k];
        const float offx = omb[px * OMS + 2 * k + 1];
        const float mr = omb[px * OMS + 18 + k];
        const float mk = 1.f / (1.f + __expf(-mr));
        const int ki = k / 3, kj = k - ki * 3;
        const float py = (float)(h + ki - 1) + offy;
        const float pxf = (float)(wcol + kj - 1) + offx;
        const float y0f = floorf(py), x0f = floorf(pxf);
        const int y0i = (int)y0f, x0i = (int)x0f;
        const int y1i = y0i + 1, x1i = x0i + 1;
        const float wy1 = py - y0f, wy0 = 1.f - wy1;
        const float wx1 = pxf - x0f, wx0 = 1.f - wx1;
        const bool vy0 = (unsigned)y0i < (unsigned)H_;
        const bool vy1 = (unsigned)y1i < (unsigned)H_;
        const bool vx0 = (unsigned)x0i < (unsigned)W_;
        const bool vx1 = (unsigned)x1i < (unsigned)W_;
        const int y0c = min(max(y0i, 0), H_ - 1), y1c = min(max(y1i, 0), H_ - 1);
        const int x0c = min(max(x0i, 0), W_ - 1), x1c = min(max(x1i, 0), W_ - 1);
        const float w00 = wy0 * wx0 * ((vy0 && vx0) ? mk : 0.f);
        const float w01 = wy0 * wx1 * ((vy0 && vx1) ? mk : 0.f);
        const float w10 = wy1 * wx0 * ((vy1 && vx0) ? mk : 0.f);
        const float w11 = wy1 * wx1 * ((vy1 && vx1) ? mk : 0.f);

        // NHWC: one corner = 16 contiguous channels = one 64B line = 4x dwordx4.
        const float* p00 = xTb + ((size_t)(y0c * W_ + x0c) << 6) + gc;
        const float* p01 = xTb + ((size_t)(y0c * W_ + x1c) << 6) + gc;
        const float* p10 = xTb + ((size_t)(y1c * W_ + x0c) << 6) + gc;
        const float* p11 = xTb + ((size_t)(y1c * W_ + x1c) << 6) + gc;
        f32x4 c00[4], c01[4], c10[4], c11[4];
#pragma unroll
        for (int j = 0; j < 4; ++j) {
            c00[j] = *(const f32x4*)(p00 + 4 * j);
            c01[j] = *(const f32x4*)(p01 + 4 * j);
            c10[j] = *(const f32x4*)(p10 + 4 * j);
            c11[j] = *(const f32x4*)(p11 + 4 * j);
        }
#pragma unroll
        for (int j = 0; j < 4; ++j) {
            f32x4 s = c00[j] * w00 + c01[j] * w01 + c10[j] * w10 + c11[j] * w11;
            fp16x2 q01 = __builtin_amdgcn_cvt_pkrtz(s[0], s[1]);
            fp16x2 q23 = __builtin_amdgcn_cvt_pkrtz(s[2], s[3]);
            pnl[2 * j]     = __builtin_bit_cast(unsigned, q01);
            pnl[2 * j + 1] = __builtin_bit_cast(unsigned, q23);
        }
    };

    sample_tap(0);
#pragma unroll 1
    for (int k = 0; k < 9; ++k) {
        _Float16* sbw = sb[k & 1];
        uint4v pa = {pnl[0], pnl[1], pnl[2], pnl[3]};
        uint4v pb = {pnl[4], pnl[5], pnl[6], pnl[7]};
        *(uint4v*)&sbw[swz(px, (g << 4))]     = pa;
        *(uint4v*)&sbw[swz(px, (g << 4) + 8)] = pb;
        if (k < 8) sample_tap(k + 1);         // gathers overlap; stores carry 8 regs only
        __builtin_amdgcn_s_waitcnt(0xC07F);   // lgkm only — vm loads keep flying
        __builtin_amdgcn_s_barrier();
        const _Float16* sbr = sb[k & 1];
#pragma unroll
        for (int s = 0; s < 4; ++s) {
            const int koff = (s << 4) + kq2;
            half8v a  = *(const half8v*)&sbr[swz(mrow, koff)];
            half8v bw = *(const half8v*)&Wch[nrow * 576 + k * 64 + koff];
            acc = __builtin_amdgcn_mfma_f32_32x32x16_f16(a, bw, acc, 0, 0, 0);
        }
        // no trailing barrier: buf[k&1] next overwritten at k+2, after barrier k+1
    }

    // ================= epilogue: store C (32x32 layout, verified R3) =======
    {
        float* ob = out + ((size_t)b * O_ + nrow) * HW_ + h * W_ + wcol0;
        const int rbase = ((lane >> 5) << 2) + (mhalf << 5);
#pragma unroll
        for (int q = 0; q < 4; ++q) {
            f32x4 vv = {acc[4 * q], acc[4 * q + 1], acc[4 * q + 2], acc[4 * q + 3]};
            *(f32x4*)&ob[rbase + 8 * q] = vv;
        }
    }
}

extern "C" void kernel_launch(void* const* d_in, const int* in_sizes, int n_in,
                              void* d_out, int out_size, void* d_ws, size_t ws_size,
                              hipStream_t stream) {
    const float* x      = (const float*)d_in[0];
    const float* w_conv = (const float*)d_in[1];
    const float* w_off  = (const float*)d_in[2];
    const float* w_msk  = (const float*)d_in[3];
    float* out = (float*)d_out;

    float* xT = (float*)d_ws;                         // 8*16384*64 f32 = 33.55 MB
    _Float16* Wch = (_Float16*)(xT + (size_t)B_ * HW_ * 64);   // 64*576 halfs
    short* Womhi  = (short*)(Wch + 64 * 576);         // 32*576
    short* Womlo  = Womhi + 32 * 576;

    prep_weights<<<144, 256, 0, stream>>>(w_conv, w_off, w_msk, Wch, Womhi, Womlo);
    transpose_x<<<2048, 256, 0, stream>>>(x, xT);

    deform_mfma<<<2048, 256, 0, stream>>>(xT, Wch, Womhi, Womlo, out);
}

// Round 2
// 212.934 us; speedup vs baseline: 1.7819x; 1.6234x over previous
//
#include <hip/hip_runtime.h>
#include <math.h>

#define B_ 8
#define C_ 64
#define H_ 128
#define W_ 128
#define O_ 64
#define HW_ (H_ * W_)
#define OMS 29     // floats per om row (odd stride -> conflict-free b32)

typedef short    short8v __attribute__((ext_vector_type(8)));
typedef _Float16 half8v  __attribute__((ext_vector_type(8)));
typedef __fp16   fp16x2  __attribute__((ext_vector_type(2)));
typedef float    f32x4   __attribute__((ext_vector_type(4)));
typedef float    f32x16  __attribute__((ext_vector_type(16)));
typedef unsigned uint4v  __attribute__((ext_vector_type(4)));

// XOR-granule swizzle for phase-A sb: row of 64 halfs = 8 granules of 16B.
__device__ __forceinline__ int swz(int row, int col) {
    return (row << 6) + ((((col >> 3) ^ (row & 7)) << 3)) + (col & 7);
}

__device__ __forceinline__ unsigned pack_bf16_pair(unsigned u0, unsigned u1) {
    return (u1 & 0xffff0000u) | (u0 >> 16);
}
__device__ __forceinline__ void split_rtne(float v, short* hi, short* lo) {
    unsigned u = __float_as_uint(v);
    unsigned r = (u + 0x7fffu + ((u >> 16) & 1u)) & 0xffff0000u;
    *hi = (short)(r >> 16);
    float rem = v - __uint_as_float(r);
    unsigned u2 = __float_as_uint(rem);
    unsigned r2 = (u2 + 0x7fffu + ((u2 >> 16) & 1u));
    *lo = (short)(r2 >> 16);
}

// Async global->LDS, 16B per lane, dest = uniform base + lane*16 (HW rule).
__device__ __forceinline__ void load_lds16(const void* g, void* l) {
    __builtin_amdgcn_global_load_lds((const __attribute__((address_space(1))) void*)g,
                                     (__attribute__((address_space(3))) void*)l, 16, 0, 0);
}

// ws: Wch2[9*4*2*512] f16 packed per (tap,s,nhalf) lane-blocks; Womhi/Womlo[32*576] bf16
__global__ void prep_weights(const float* __restrict__ wc,
                             const float* __restrict__ wo,
                             const float* __restrict__ wm,
                             _Float16* __restrict__ Wch2,
                             short* __restrict__ Womhi, short* __restrict__ Womlo)
{
    int tid = blockIdx.x * blockDim.x + threadIdx.x;
    if (tid < 9 * 4096) {   // Wch2: packed so one wave-instr reads 16 consecutive lines
        int j = tid & 7, l = (tid >> 3) & 63, nh = (tid >> 9) & 1, s = (tid >> 10) & 3, tap = tid >> 12;
        int o = nh * 32 + (l & 31);
        int c = s * 16 + ((l >> 5) << 3) + j;
        Wch2[tid] = (_Float16)wc[(o * 64 + c) * 9 + tap];
    }
    if (tid < 32 * 576) {
        int n = tid / 576, tk = tid % 576;
        int tap = tk >> 6, c = tk & 63;
        float v = 0.f;
        if (n < 18)      v = wo[(n * 64 + c) * 9 + tap];
        else if (n < 27) v = wm[((n - 18) * 64 + c) * 9 + tap];
        split_rtne(v, &Womhi[tid], &Womlo[tid]);
    }
}

// NCHW f32 -> NHWC fp16. Pixel row = 64ch * 2B = 128B = 2 cachelines (was 4 as f32).
__global__ __launch_bounds__(256) void transpose_x(const float* __restrict__ x,
                                                   _Float16* __restrict__ xT)
{
    __shared__ float tile[64][65];
    const int t = threadIdx.x;
    const int b = blockIdx.x & 7;
    const int tp = blockIdx.x >> 3;        // 0..255: 64-pixel tile within HW
    const int lane = t & 63, wv = t >> 6;
    const float* xb = x + (size_t)b * C_ * HW_;
    const int p0 = tp * 64;
#pragma unroll
    for (int j = 0; j < 16; ++j) {
        int c = wv * 16 + j;
        tile[c][lane] = xb[(size_t)c * HW_ + p0 + lane];   // 256B coalesced
    }
    __syncthreads();
    _Float16* ob = xT + ((size_t)b * HW_ + p0) * 64;
    const int px = t >> 2, c0 = (t & 3) * 16;
    half8v h0, h1;
#pragma unroll
    for (int j = 0; j < 8; ++j) h0[j] = (_Float16)tile[c0 + j][px];
#pragma unroll
    for (int j = 0; j < 8; ++j) h1[j] = (_Float16)tile[c0 + 8 + j][px];
    *(half8v*)&ob[(size_t)px * 64 + c0] = h0;
    *(half8v*)&ob[(size_t)px * 64 + c0 + 8] = h1;
}

__global__ __launch_bounds__(256, 4) void deform_mfma(
    const float* __restrict__ x,           // NCHW f32 (phase A, exact numerics)
    const _Float16* __restrict__ xT,       // NHWC fp16 (phase B corner strips)
    const _Float16* __restrict__ Wch2,
    const short* __restrict__ Womhi, const short* __restrict__ Womlo,
    float* __restrict__ out)
{
    // union: phase A sb[2][64*64] halfs (16KB) / phase B corner strip (32KB)
    __shared__ char uni[32768];
    __shared__ float omb[64 * OMS];
    _Float16* sb0  = (_Float16*)uni;
    _Float16* sb1  = sb0 + 4096;
    _Float16* strB = (_Float16*)uni;       // [corner][px][64 halfs], 256 rows * 128B

    const int t = threadIdx.x;
    const int lane = t & 63;
    const int wv = t >> 6;
    const int px = lane;
    const int g = __builtin_amdgcn_readfirstlane(wv);

    const int blk = blockIdx.x;
    const int b = blk & 7;                 // XCD-batch swizzle (verified R5)
    const int rest = blk >> 3;
    const int wcol0 = (rest & 1) << 6;
    const int h = rest >> 1;
    const float* xb = x + (size_t)b * C_ * HW_;
    const float* xg = xb + (size_t)(g * 16) * HW_;   // wave-uniform channel-group base
    const _Float16* xTb = xT + (size_t)b * HW_ * 64;
    const int wcol = wcol0 + px;

    // ================= phase A: offset/mask conv via MFMA (bf16x3, R0-verified) =====
    f32x4 cv0 = {}, cv1 = {};
    float av[16];
    float okn;
    {
        int yy = h - 1, xx = wcol - 1;
        okn = (((unsigned)yy < (unsigned)H_) && ((unsigned)xx < (unsigned)W_)) ? 1.f : 0.f;
        int yyc = min(max(yy, 0), H_ - 1), xxc = min(max(xx, 0), W_ - 1);
        int voff = yyc * W_ + xxc;
#pragma unroll
        for (int j = 0; j < 16; ++j) av[j] = xg[(size_t)j * HW_ + voff];
    }
    const int mrowA = (wv << 4) + (lane & 15);
    const int kqA = (lane >> 4) << 3;
    const int n0 = lane & 15;

#pragma unroll 1
    for (int tap = 0; tap < 9; ++tap) {
        const float okc = okn;
#pragma unroll
        for (int i = 0; i < 4; ++i) {
            float s0 = av[4*i+0] * okc, s1 = av[4*i+1] * okc;
            float s2 = av[4*i+2] * okc, s3 = av[4*i+3] * okc;
            unsigned u0 = __float_as_uint(s0), u1 = __float_as_uint(s1);
            unsigned u2 = __float_as_uint(s2), u3 = __float_as_uint(s3);
            uint2 hv, lv;
            hv.x = pack_bf16_pair(u0, u1);
            hv.y = pack_bf16_pair(u2, u3);
            lv.x = pack_bf16_pair(__float_as_uint(s0 - __uint_as_float(u0 & 0xffff0000u)),
                                  __float_as_uint(s1 - __uint_as_float(u1 & 0xffff0000u)));
            lv.y = pack_bf16_pair(__float_as_uint(s2 - __uint_as_float(u2 & 0xffff0000u)),
                                  __float_as_uint(s3 - __uint_as_float(u3 & 0xffff0000u)));
            const int off = swz(px, (g << 4) + (i << 2));
            *(uint2*)&sb0[off] = hv;
            *(uint2*)&sb1[off] = lv;
        }
        if (tap < 8) {   // prefetch next tap's coalesced loads; fly across barrier
            int tn = tap + 1, ty = tn / 3, tx = tn - ty * 3;
            int yy = h + ty - 1, xx = wcol + tx - 1;
            okn = (((unsigned)yy < (unsigned)H_) && ((unsigned)xx < (unsigned)W_)) ? 1.f : 0.f;
            int yyc = min(max(yy, 0), H_ - 1), xxc = min(max(xx, 0), W_ - 1);
            int voff = yyc * W_ + xxc;
#pragma unroll
            for (int j = 0; j < 16; ++j) av[j] = xg[(size_t)j * HW_ + voff];
        }
        __builtin_amdgcn_s_waitcnt(0xC07F);   // lgkmcnt(0) only — vm loads stay in flight
        __builtin_amdgcn_s_barrier();
#pragma unroll
        for (int s = 0; s < 2; ++s) {
            const int koff = (s << 5) + kqA;
            short8v ahi = *(const short8v*)&sb0[swz(mrowA, koff)];
            short8v alo = *(const short8v*)&sb1[swz(mrowA, koff)];
            const int kg = tap * 64 + koff;
            short8v bh0 = *(const short8v*)&Womhi[n0 * 576 + kg];
            short8v bl0 = *(const short8v*)&Womlo[n0 * 576 + kg];
            short8v bh1 = *(const short8v*)&Womhi[(n0 + 16) * 576 + kg];
            short8v bl1 = *(const short8v*)&Womlo[(n0 + 16) * 576 + kg];
            cv0 = __builtin_amdgcn_mfma_f32_16x16x32_bf16(ahi, bh0, cv0, 0, 0, 0);
            cv0 = __builtin_amdgcn_mfma_f32_16x16x32_bf16(ahi, bl0, cv0, 0, 0, 0);
            cv0 = __builtin_amdgcn_mfma_f32_16x16x32_bf16(alo, bh0, cv0, 0, 0, 0);
            cv1 = __builtin_amdgcn_mfma_f32_16x16x32_bf16(ahi, bh1, cv1, 0, 0, 0);
            cv1 = __builtin_amdgcn_mfma_f32_16x16x32_bf16(ahi, bl1, cv1, 0, 0, 0);
            cv1 = __builtin_amdgcn_mfma_f32_16x16x32_bf16(alo, bh1, cv1, 0, 0, 0);
        }
        __builtin_amdgcn_s_barrier();   // reads consumed -> safe rewrite
    }

    // scatter om (verified layout)
    {
        const int j0 = lane & 15;
        const int pxo = (wv << 4) + ((lane >> 4) << 2);
#pragma unroll
        for (int r = 0; r < 4; ++r) {
            omb[(pxo + r) * OMS + j0] = cv0[r];
            if (j0 < 13) omb[(pxo + r) * OMS + j0 + 16] = cv1[r];
        }
    }
    __builtin_amdgcn_s_waitcnt(0xC07F);
    __builtin_amdgcn_s_barrier();
    // sb is dead from here; strB (same memory) takes over.

    // ================= phase B: cooperative corner fill + direct-reg einsum =====
    f32x16 acc = {};
    const int mhalf = wv & 1, nhalf = wv >> 1;
    const int mrow = (mhalf << 5) + (lane & 31);
    const int nrow = (nhalf << 5) + (lane & 31);
    const int kchunk = lane >> 5;          // 0/1: which 16B chunk pair
    const int fpx0 = lane >> 3;            // fill: row-within-8
    const int fslot = lane & 7;            // fill: 16B slot
    const int dy = g >> 1, dx = g & 1;     // wave g loads corner g

#pragma unroll 1
    for (int k = 0; k < 9; ++k) {
        const int ki = k / 3, kj = k - ki * 3;
        // ---- fill: wave g loads corner (dy,dx) rows for all 64 px, full-line coop.
        // LDS dest linear in lane; bank-decollision via pre-swizzled GLOBAL chunk.
#pragma unroll
        for (int i = 0; i < 8; ++i) {
            const int p = (i << 3) + fpx0;
            const float offy = omb[p * OMS + 2 * k];
            const float offx = omb[p * OMS + 2 * k + 1];
            const float py  = (float)(h + ki - 1) + offy;
            const float pxf = (float)(wcol0 + p + kj - 1) + offx;
            const int yc = min(max((int)floorf(py)  + dy, 0), H_ - 1);
            const int xc = min(max((int)floorf(pxf) + dx, 0), W_ - 1);
            const _Float16* src = xTb + ((size_t)((yc << 7) + xc) << 6) + ((fslot ^ (p & 7)) << 3);
            load_lds16(src, &strB[(((g << 6) + (i << 3)) << 6) + (lane << 3)]);
        }

        // ---- per-lane bilinear weights for own pixel (overlaps load flight)
        const float offy = omb[mrow * OMS + 2 * k];
        const float offx = omb[mrow * OMS + 2 * k + 1];
        const float mr   = omb[mrow * OMS + 18 + k];
        const float mk = 1.f / (1.f + __expf(-mr));
        const float py  = (float)(h + ki - 1) + offy;
        const float pxf = (float)(wcol0 + mrow + kj - 1) + offx;
        const float y0f = floorf(py), x0f = floorf(pxf);
        const int y0i = (int)y0f, x0i = (int)x0f;
        const float wy1 = py - y0f, wy0 = 1.f - wy1;
        const float wx1 = pxf - x0f, wx0 = 1.f - wx1;
        const bool vy0 = (unsigned)y0i < (unsigned)H_;
        const bool vy1 = (unsigned)(y0i + 1) < (unsigned)H_;
        const bool vx0 = (unsigned)x0i < (unsigned)W_;
        const bool vx1 = (unsigned)(x0i + 1) < (unsigned)W_;
        const float w00 = wy0 * wx0 * ((vy0 && vx0) ? mk : 0.f);
        const float w01 = wy0 * wx1 * ((vy0 && vx1) ? mk : 0.f);
        const float w10 = wy1 * wx0 * ((vy1 && vx0) ? mk : 0.f);
        const float w11 = wy1 * wx1 * ((vy1 && vx1) ? mk : 0.f);

        __builtin_amdgcn_s_waitcnt(0x0F70);   // vmcnt(0): strip loads landed
        __builtin_amdgcn_s_barrier();

        const int rsw = mrow & 7;
#pragma unroll
        for (int s = 0; s < 4; ++s) {
            const int slot = ((s << 1) + kchunk) ^ rsw;
            const _Float16* r0 = &strB[(mrow << 6) + (slot << 3)];
            half8v v00 = *(const half8v*)(r0);            // corner (y0,x0)
            half8v v01 = *(const half8v*)(r0 + 4096);     // corner (y0,x1)
            half8v v10 = *(const half8v*)(r0 + 8192);     // corner (y1,x0)
            half8v v11 = *(const half8v*)(r0 + 12288);    // corner (y1,x1)
            unsigned pr[4];
#pragma unroll
            for (int jj = 0; jj < 4; ++jj) {
                float s0 = w00 * (float)v00[2*jj]   + w01 * (float)v01[2*jj]
                         + w10 * (float)v10[2*jj]   + w11 * (float)v11[2*jj];
                float s1 = w00 * (float)v00[2*jj+1] + w01 * (float)v01[2*jj+1]
                         + w10 * (float)v10[2*jj+1] + w11 * (float)v11[2*jj+1];
                fp16x2 pq = __builtin_amdgcn_cvt_pkrtz(s0, s1);
                pr[jj] = __builtin_bit_cast(unsigned, pq);
            }
            half8v a = __builtin_bit_cast(half8v, (uint4v){pr[0], pr[1], pr[2], pr[3]});
            half8v bw = *(const half8v*)&Wch2[(((((k << 2) + s) << 1) + nhalf) << 9) + (lane << 3)];
            acc = __builtin_amdgcn_mfma_f32_32x32x16_f16(a, bw, acc, 0, 0, 0);
        }
        __builtin_amdgcn_s_barrier();        // all reads done -> strip reusable
    }

    // ================= epilogue: store C (32x32 layout, verified R3) =======
    {
        float* ob = out + ((size_t)b * O_ + nrow) * HW_ + h * W_ + wcol0;
        const int rbase = ((lane >> 5) << 2) + (mhalf << 5);
#pragma unroll
        for (int q = 0; q < 4; ++q) {
            f32x4 vv = {acc[4*q], acc[4*q+1], acc[4*q+2], acc[4*q+3]};
            *(f32x4*)&ob[rbase + 8*q] = vv;
        }
    }
}

extern "C" void kernel_launch(void* const* d_in, const int* in_sizes, int n_in,
                              void* d_out, int out_size, void* d_ws, size_t ws_size,
                              hipStream_t stream) {
    const float* x      = (const float*)d_in[0];
    const float* w_conv = (const float*)d_in[1];
    const float* w_off  = (const float*)d_in[2];
    const float* w_msk  = (const float*)d_in[3];
    float* out = (float*)d_out;

    _Float16* xT  = (_Float16*)d_ws;                        // 8*16384*64 halfs = 16.78 MB
    _Float16* Wch2 = xT + (size_t)B_ * HW_ * 64;            // 9*4096 halfs
    short* Womhi  = (short*)(Wch2 + 9 * 4096);              // 32*576
    short* Womlo  = Womhi + 32 * 576;

    prep_weights<<<144, 256, 0, stream>>>(w_conv, w_off, w_msk, Wch2, Womhi, Womlo);
    transpose_x<<<2048, 256, 0, stream>>>(x, xT);

    deform_mfma<<<2048, 256, 0, stream>>>(x, xT, Wch2, Womhi, Womlo, out);
}

// Round 5
// 209.551 us; speedup vs baseline: 1.8107x; 1.0161x over previous
//
#include <hip/hip_runtime.h>
#include <math.h>

#define B_ 8
#define C_ 64
#define H_ 128
#define W_ 128
#define O_ 64
#define HW_ (H_ * W_)
#define OMS 29     // floats per om row (odd stride -> conflict-free b32)

typedef short    short8v __attribute__((ext_vector_type(8)));
typedef _Float16 half8v  __attribute__((ext_vector_type(8)));
typedef float    f32x4   __attribute__((ext_vector_type(4)));
typedef float    f32x16  __attribute__((ext_vector_type(16)));
typedef unsigned uint4v  __attribute__((ext_vector_type(4)));

// XOR-granule swizzle for phase-A sb: row of 64 halfs = 8 granules of 16B.
__device__ __forceinline__ int swz(int row, int col) {
    return (row << 6) + ((((col >> 3) ^ (row & 7)) << 3)) + (col & 7);
}

__device__ __forceinline__ unsigned pack_bf16_pair(unsigned u0, unsigned u1) {
    return (u1 & 0xffff0000u) | (u0 >> 16);
}
__device__ __forceinline__ void split_rtne(float v, short* hi, short* lo) {
    unsigned u = __float_as_uint(v);
    unsigned r = (u + 0x7fffu + ((u >> 16) & 1u)) & 0xffff0000u;
    *hi = (short)(r >> 16);
    float rem = v - __uint_as_float(r);
    unsigned u2 = __float_as_uint(rem);
    unsigned r2 = (u2 + 0x7fffu + ((u2 >> 16) & 1u));
    *lo = (short)(r2 >> 16);
}

// Async global->LDS, 16B per lane, dest = uniform base + lane*16 (HW rule).
__device__ __forceinline__ void load_lds16(const void* g, void* l) {
    __builtin_amdgcn_global_load_lds((const __attribute__((address_space(1))) void*)g,
                                     (__attribute__((address_space(3))) void*)l, 16, 0, 0);
}

// ws: Wch2[9*4*2*512] f16 packed per (tap,s,nhalf) lane-blocks; Womhi/Womlo[32*576] bf16
__global__ void prep_weights(const float* __restrict__ wc,
                             const float* __restrict__ wo,
                             const float* __restrict__ wm,
                             _Float16* __restrict__ Wch2,
                             short* __restrict__ Womhi, short* __restrict__ Womlo)
{
    int tid = blockIdx.x * blockDim.x + threadIdx.x;
    if (tid < 9 * 4096) {   // Wch2: packed so one wave-instr reads 16 consecutive lines
        int j = tid & 7, l = (tid >> 3) & 63, nh = (tid >> 9) & 1, s = (tid >> 10) & 3, tap = tid >> 12;
        int o = nh * 32 + (l & 31);
        int c = s * 16 + ((l >> 5) << 3) + j;
        Wch2[tid] = (_Float16)wc[(o * 64 + c) * 9 + tap];
    }
    if (tid < 32 * 576) {
        int n = tid / 576, tk = tid % 576;
        int tap = tk >> 6, c = tk & 63;
        float v = 0.f;
        if (n < 18)      v = wo[(n * 64 + c) * 9 + tap];
        else if (n < 27) v = wm[((n - 18) * 64 + c) * 9 + tap];
        split_rtne(v, &Womhi[tid], &Womlo[tid]);
    }
}

// NCHW f32 -> NHWC fp16. Pixel row = 64ch * 2B = 128B = 2 cachelines.
__global__ __launch_bounds__(256) void transpose_x(const float* __restrict__ x,
                                                   _Float16* __restrict__ xT)
{
    __shared__ float tile[64][65];
    const int t = threadIdx.x;
    const int b = blockIdx.x & 7;
    const int tp = blockIdx.x >> 3;        // 0..255: 64-pixel tile within HW
    const int lane = t & 63, wv = t >> 6;
    const float* xb = x + (size_t)b * C_ * HW_;
    const int p0 = tp * 64;
#pragma unroll
    for (int j = 0; j < 16; ++j) {
        int c = wv * 16 + j;
        tile[c][lane] = xb[(size_t)c * HW_ + p0 + lane];   // 256B coalesced
    }
    __syncthreads();
    _Float16* ob = xT + ((size_t)b * HW_ + p0) * 64;
    const int px = t >> 2, c0 = (t & 3) * 16;
    half8v h0, h1;
#pragma unroll
    for (int j = 0; j < 8; ++j) h0[j] = (_Float16)tile[c0 + j][px];
#pragma unroll
    for (int j = 0; j < 8; ++j) h1[j] = (_Float16)tile[c0 + 8 + j][px];
    *(half8v*)&ob[(size_t)px * 64 + c0] = h0;
    *(half8v*)&ob[(size_t)px * 64 + c0 + 8] = h1;
}

__global__ __launch_bounds__(256, 4) void deform_mfma(
    const float* __restrict__ x,           // NCHW f32 (phase A, exact numerics)
    const _Float16* __restrict__ xT,       // NHWC fp16 (phase B corner strips)
    const _Float16* __restrict__ Wch2,
    const short* __restrict__ Womhi, const short* __restrict__ Womlo,
    float* __restrict__ out)
{
    // union: phase A sb[2][64*64] halfs (16KB) / phase B corner strip (32KB)
    __shared__ char uni[32768];
    __shared__ float omb[64 * OMS];
    _Float16* sb0  = (_Float16*)uni;
    _Float16* sb1  = sb0 + 4096;
    _Float16* strB = (_Float16*)uni;       // [corner][px][64 halfs], 256 rows * 128B

    const int t = threadIdx.x;
    const int lane = t & 63;
    const int wv = t >> 6;
    const int px = lane;
    const int g = __builtin_amdgcn_readfirstlane(wv);

    const int blk = blockIdx.x;
    const int b = blk & 7;                 // XCD-batch swizzle (verified R5)
    const int rest = blk >> 3;
    const int wcol0 = (rest & 1) << 6;
    const int h = rest >> 1;
    const float* xb = x + (size_t)b * C_ * HW_;
    const float* xg = xb + (size_t)(g * 16) * HW_;   // wave-uniform channel-group base
    const _Float16* xTb = xT + (size_t)b * HW_ * 64;
    const int wcol = wcol0 + px;

    // ================= phase A: offset/mask conv via MFMA (bf16x3, R0-verified) =====
    f32x4 cv0 = {}, cv1 = {};
    float av[16];
    float okn;
    {
        int yy = h - 1, xx = wcol - 1;
        okn = (((unsigned)yy < (unsigned)H_) && ((unsigned)xx < (unsigned)W_)) ? 1.f : 0.f;
        int yyc = min(max(yy, 0), H_ - 1), xxc = min(max(xx, 0), W_ - 1);
        int voff = yyc * W_ + xxc;
#pragma unroll
        for (int j = 0; j < 16; ++j) av[j] = xg[(size_t)j * HW_ + voff];
    }
    const int mrowA = (wv << 4) + (lane & 15);
    const int kqA = (lane >> 4) << 3;
    const int n0 = lane & 15;

#pragma unroll 1
    for (int tap = 0; tap < 9; ++tap) {
        const float okc = okn;
#pragma unroll
        for (int i = 0; i < 4; ++i) {
            float s0 = av[4*i+0] * okc, s1 = av[4*i+1] * okc;
            float s2 = av[4*i+2] * okc, s3 = av[4*i+3] * okc;
            unsigned u0 = __float_as_uint(s0), u1 = __float_as_uint(s1);
            unsigned u2 = __float_as_uint(s2), u3 = __float_as_uint(s3);
            uint2 hv, lv;
            hv.x = pack_bf16_pair(u0, u1);
            hv.y = pack_bf16_pair(u2, u3);
            lv.x = pack_bf16_pair(__float_as_uint(s0 - __uint_as_float(u0 & 0xffff0000u)),
                                  __float_as_uint(s1 - __uint_as_float(u1 & 0xffff0000u)));
            lv.y = pack_bf16_pair(__float_as_uint(s2 - __uint_as_float(u2 & 0xffff0000u)),
                                  __float_as_uint(s3 - __uint_as_float(u3 & 0xffff0000u)));
            const int off = swz(px, (g << 4) + (i << 2));
            *(uint2*)&sb0[off] = hv;
            *(uint2*)&sb1[off] = lv;
        }
        if (tap < 8) {   // prefetch next tap's coalesced loads; fly across barrier
            int tn = tap + 1, ty = tn / 3, tx = tn - ty * 3;
            int yy = h + ty - 1, xx = wcol + tx - 1;
            okn = (((unsigned)yy < (unsigned)H_) && ((unsigned)xx < (unsigned)W_)) ? 1.f : 0.f;
            int yyc = min(max(yy, 0), H_ - 1), xxc = min(max(xx, 0), W_ - 1);
            int voff = yyc * W_ + xxc;
#pragma unroll
            for (int j = 0; j < 16; ++j) av[j] = xg[(size_t)j * HW_ + voff];
        }
        __builtin_amdgcn_s_waitcnt(0xC07F);   // lgkmcnt(0) only — vm loads stay in flight
        __builtin_amdgcn_s_barrier();
#pragma unroll
        for (int s = 0; s < 2; ++s) {
            const int koff = (s << 5) + kqA;
            short8v ahi = *(const short8v*)&sb0[swz(mrowA, koff)];
            short8v alo = *(const short8v*)&sb1[swz(mrowA, koff)];
            const int kg = tap * 64 + koff;
            short8v bh0 = *(const short8v*)&Womhi[n0 * 576 + kg];
            short8v bl0 = *(const short8v*)&Womlo[n0 * 576 + kg];
            short8v bh1 = *(const short8v*)&Womhi[(n0 + 16) * 576 + kg];
            short8v bl1 = *(const short8v*)&Womlo[(n0 + 16) * 576 + kg];
            cv0 = __builtin_amdgcn_mfma_f32_16x16x32_bf16(ahi, bh0, cv0, 0, 0, 0);
            cv0 = __builtin_amdgcn_mfma_f32_16x16x32_bf16(ahi, bl0, cv0, 0, 0, 0);
            cv0 = __builtin_amdgcn_mfma_f32_16x16x32_bf16(alo, bh0, cv0, 0, 0, 0);
            cv1 = __builtin_amdgcn_mfma_f32_16x16x32_bf16(ahi, bh1, cv1, 0, 0, 0);
            cv1 = __builtin_amdgcn_mfma_f32_16x16x32_bf16(ahi, bl1, cv1, 0, 0, 0);
            cv1 = __builtin_amdgcn_mfma_f32_16x16x32_bf16(alo, bh1, cv1, 0, 0, 0);
        }
        __builtin_amdgcn_s_barrier();   // reads consumed -> safe rewrite
    }

    // scatter om (verified layout)
    {
        const int j0 = lane & 15;
        const int pxo = (wv << 4) + ((lane >> 4) << 2);
#pragma unroll
        for (int r = 0; r < 4; ++r) {
            omb[(pxo + r) * OMS + j0] = cv0[r];
            if (j0 < 13) omb[(pxo + r) * OMS + j0 + 16] = cv1[r];
        }
    }
    __builtin_amdgcn_s_waitcnt(0xC07F);
    __builtin_amdgcn_s_barrier();
    // sb is dead from here; strB (same memory) takes over.

    // ================= phase B: cooperative corner fill + packed-fp16 einsum =====
    f32x16 acc = {};
    const int mhalf = wv & 1, nhalf = wv >> 1;
    const int mrow = (mhalf << 5) + (lane & 31);
    const int nrow = (nhalf << 5) + (lane & 31);
    const int kchunk = lane >> 5;          // 0/1: which 16B chunk pair
    const int fpx0 = lane >> 3;            // fill: row-within-8
    const int fslot = lane & 7;            // fill: 16B slot
    const int dy = g >> 1, dx = g & 1;     // wave g loads corner g

#pragma unroll 1
    for (int k = 0; k < 9; ++k) {
        const int ki = k / 3, kj = k - ki * 3;
        // ---- fill: wave g loads corner (dy,dx) rows for all 64 px, full-line coop.
        // LDS dest linear in lane; bank-decollision via pre-swizzled GLOBAL chunk.
#pragma unroll
        for (int i = 0; i < 8; ++i) {
            const int p = (i << 3) + fpx0;
            const float offy = omb[p * OMS + 2 * k];
            const float offx = omb[p * OMS + 2 * k + 1];
            const float py  = (float)(h + ki - 1) + offy;
            const float pxf = (float)(wcol0 + p + kj - 1) + offx;
            const int yc = min(max((int)floorf(py)  + dy, 0), H_ - 1);
            const int xc = min(max((int)floorf(pxf) + dx, 0), W_ - 1);
            const _Float16* src = xTb + ((size_t)((yc << 7) + xc) << 6) + ((fslot ^ (p & 7)) << 3);
            load_lds16(src, &strB[(((g << 6) + (i << 3)) << 6) + (lane << 3)]);
        }

        // ---- per-lane bilinear weights for own pixel (overlaps load flight; R2 math)
        const float offy = omb[mrow * OMS + 2 * k];
        const float offx = omb[mrow * OMS + 2 * k + 1];
        const float mr   = omb[mrow * OMS + 18 + k];
        const float mk = 1.f / (1.f + __expf(-mr));
        const float py  = (float)(h + ki - 1) + offy;
        const float pxf = (float)(wcol0 + mrow + kj - 1) + offx;
        const float y0f = floorf(py), x0f = floorf(pxf);
        const int y0i = (int)y0f, x0i = (int)x0f;
        const float wy1 = py - y0f, wy0 = 1.f - wy1;
        const float wx1 = pxf - x0f, wx0 = 1.f - wx1;
        const bool vy0 = (unsigned)y0i < (unsigned)H_;
        const bool vy1 = (unsigned)(y0i + 1) < (unsigned)H_;
        const bool vx0 = (unsigned)x0i < (unsigned)W_;
        const bool vx1 = (unsigned)(x0i + 1) < (unsigned)W_;
        const float w00 = wy0 * wx0 * ((vy0 && vx0) ? mk : 0.f);
        const float w01 = wy0 * wx1 * ((vy0 && vx1) ? mk : 0.f);
        const float w10 = wy1 * wx0 * ((vy1 && vx0) ? mk : 0.f);
        const float w11 = wy1 * wx1 * ((vy1 && vx1) ? mk : 0.f);
        const _Float16 hw00 = (_Float16)w00, hw01 = (_Float16)w01;
        const _Float16 hw10 = (_Float16)w10, hw11 = (_Float16)w11;

        __builtin_amdgcn_s_waitcnt(0x0F70);   // vmcnt(0): strip loads landed
        __builtin_amdgcn_s_barrier();

        const int rsw = mrow & 7;
#pragma unroll
        for (int s = 0; s < 4; ++s) {
            const int slot = ((s << 1) + kchunk) ^ rsw;
            const _Float16* r0 = &strB[(mrow << 6) + (slot << 3)];
            half8v v00 = *(const half8v*)(r0);            // corner (y0,x0)
            half8v v01 = *(const half8v*)(r0 + 4096);     // corner (y0,x1)
            half8v v10 = *(const half8v*)(r0 + 8192);     // corner (y1,x0)
            half8v v11 = *(const half8v*)(r0 + 12288);    // corner (y1,x1)
            half8v a = v00 * hw00;                        // v_pk_mul/fma_f16 chain
            a = v01 * hw01 + a;
            a = v10 * hw10 + a;
            a = v11 * hw11 + a;
            half8v bw = *(const half8v*)&Wch2[(((((k << 2) + s) << 1) + nhalf) << 9) + (lane << 3)];
            acc = __builtin_amdgcn_mfma_f32_32x32x16_f16(a, bw, acc, 0, 0, 0);
        }
        __builtin_amdgcn_s_barrier();        // all reads done -> strip reusable
    }

    // ================= epilogue: store C (32x32 layout, verified R3) =======
    {
        float* ob = out + ((size_t)b * O_ + nrow) * HW_ + h * W_ + wcol0;
        const int rbase = ((lane >> 5) << 2) + (mhalf << 5);
#pragma unroll
        for (int q = 0; q < 4; ++q) {
            f32x4 vv = {acc[4*q], acc[4*q+1], acc[4*q+2], acc[4*q+3]};
            *(f32x4*)&ob[rbase + 8*q] = vv;
        }
    }
}

extern "C" void kernel_launch(void* const* d_in, const int* in_sizes, int n_in,
                              void* d_out, int out_size, void* d_ws, size_t ws_size,
                              hipStream_t stream) {
    const float* x      = (const float*)d_in[0];
    const float* w_conv = (const float*)d_in[1];
    const float* w_off  = (const float*)d_in[2];
    const float* w_msk  = (const float*)d_in[3];
    float* out = (float*)d_out;

    _Float16* xT  = (_Float16*)d_ws;                        // 8*16384*64 halfs = 16.78 MB
    _Float16* Wch2 = xT + (size_t)B_ * HW_ * 64;            // 9*4096 halfs
    short* Womhi  = (short*)(Wch2 + 9 * 4096);              // 32*576
    short* Womlo  = Womhi + 32 * 576;

    prep_weights<<<144, 256, 0, stream>>>(w_conv, w_off, w_msk, Wch2, Womhi, Womlo);
    transpose_x<<<2048, 256, 0, stream>>>(x, xT);

    deform_mfma<<<2048, 256, 0, stream>>>(x, xT, Wch2, Womhi, Womlo, out);
}

// Round 6
// 179.424 us; speedup vs baseline: 2.1147x; 1.1679x over previous
//
#include <hip/hip_runtime.h>
#include <math.h>

#define B_ 8
#define C_ 64
#define H_ 128
#define W_ 128
#define O_ 64
#define HW_ (H_ * W_)
#define OMS 29     // floats per om row (odd stride -> conflict-free b32)

typedef _Float16 half8v  __attribute__((ext_vector_type(8)));
typedef float    f32x4   __attribute__((ext_vector_type(4)));
typedef float    f32x16  __attribute__((ext_vector_type(16)));
typedef unsigned uint4v  __attribute__((ext_vector_type(4)));

// Async global->LDS, 16B per lane, dest = uniform base + lane*16 (HW rule).
__device__ __forceinline__ void load_lds16(const void* g, void* l) {
    __builtin_amdgcn_global_load_lds((const __attribute__((address_space(1))) void*)g,
                                     (__attribute__((address_space(3))) void*)l, 16, 0, 0);
}

// ws: Wch2[9*4*2*512] f16 packed per (tap,s,nhalf) lane-blocks; Womh[32*576] f16
__global__ void prep_weights(const float* __restrict__ wc,
                             const float* __restrict__ wo,
                             const float* __restrict__ wm,
                             _Float16* __restrict__ Wch2,
                             _Float16* __restrict__ Womh)
{
    int tid = blockIdx.x * blockDim.x + threadIdx.x;
    if (tid < 9 * 4096) {   // Wch2: packed so one wave-instr reads 16 consecutive lines
        int j = tid & 7, l = (tid >> 3) & 63, nh = (tid >> 9) & 1, s = (tid >> 10) & 3, tap = tid >> 12;
        int o = nh * 32 + (l & 31);
        int c = s * 16 + ((l >> 5) << 3) + j;
        Wch2[tid] = (_Float16)wc[(o * 64 + c) * 9 + tap];
    }
    if (tid < 32 * 576) {   // Womh: [n][tap*64+c] fp16, rows >=27 zero
        int n = tid / 576, tk = tid % 576;
        int tap = tk >> 6, c = tk & 63;
        float v = 0.f;
        if (n < 18)      v = wo[(n * 64 + c) * 9 + tap];
        else if (n < 27) v = wm[((n - 18) * 64 + c) * 9 + tap];
        Womh[tid] = (_Float16)v;
    }
}

// NCHW f32 -> NHWC fp16. Pixel row = 64ch * 2B = 128B = 2 cachelines.
__global__ __launch_bounds__(256) void transpose_x(const float* __restrict__ x,
                                                   _Float16* __restrict__ xT)
{
    __shared__ float tile[64][65];
    const int t = threadIdx.x;
    const int b = blockIdx.x & 7;
    const int tp = blockIdx.x >> 3;        // 0..255: 64-pixel tile within HW
    const int lane = t & 63, wv = t >> 6;
    const float* xb = x + (size_t)b * C_ * HW_;
    const int p0 = tp * 64;
#pragma unroll
    for (int j = 0; j < 16; ++j) {
        int c = wv * 16 + j;
        tile[c][lane] = xb[(size_t)c * HW_ + p0 + lane];   // 256B coalesced
    }
    __syncthreads();
    _Float16* ob = xT + ((size_t)b * HW_ + p0) * 64;
    const int px = t >> 2, c0 = (t & 3) * 16;
    half8v h0, h1;
#pragma unroll
    for (int j = 0; j < 8; ++j) h0[j] = (_Float16)tile[c0 + j][px];
#pragma unroll
    for (int j = 0; j < 8; ++j) h1[j] = (_Float16)tile[c0 + 8 + j][px];
    *(half8v*)&ob[(size_t)px * 64 + c0] = h0;
    *(half8v*)&ob[(size_t)px * 64 + c0 + 8] = h1;
}

__global__ __launch_bounds__(256, 4) void deform_mfma(
    const _Float16* __restrict__ xT,       // NHWC fp16 (phases A and B)
    const _Float16* __restrict__ Wch2,
    const _Float16* __restrict__ Womh,
    float* __restrict__ out)
{
    __shared__ char uni[32768];            // phase B corner strip (phase A uses no LDS)
    __shared__ float omb[64 * OMS];
    _Float16* strB = (_Float16*)uni;       // [corner][px][64 halfs], 256 rows * 128B

    const int t = threadIdx.x;
    const int lane = t & 63;
    const int wv = t >> 6;
    const int g = __builtin_amdgcn_readfirstlane(wv);

    const int blk = blockIdx.x;
    const int b = blk & 7;                 // XCD-batch swizzle (verified R5)
    const int rest = blk >> 3;
    const int wcol0 = (rest & 1) << 6;
    const int h = rest >> 1;
    const _Float16* xTb = xT + (size_t)b * HW_ * 64;

    // ================= phase A: offset/mask conv, direct-from-xT fp16 MFMA ======
    // Lane = (pixel mrowA within strip, k-subgroup kqA). No LDS, no barriers.
    f32x4 cv0 = {}, cv1 = {};
    const int mrowA = (wv << 4) + (lane & 15);   // pixel within 64-col strip
    const int kqA = (lane >> 4) << 3;            // 8-half subgroup within K=32 block
    const int n0 = lane & 15;
    const int xxA = wcol0 + mrowA - 1;
    const int yyA = h - 1;

#pragma unroll
    for (int tap = 0; tap < 9; ++tap) {
        const int ty = tap / 3, tx = tap - ty * 3;
        const int yy = yyA + ty, xx = xxA + tx;
        const bool ok = (((unsigned)yy < (unsigned)H_) && ((unsigned)xx < (unsigned)W_));
        const _Float16 okh = ok ? (_Float16)1.0f : (_Float16)0.0f;
        const int yyc = min(max(yy, 0), H_ - 1), xxc = min(max(xx, 0), W_ - 1);
        const _Float16* prow = xTb + ((size_t)((yyc << 7) + xxc) << 6);
        const _Float16* wr = Womh + n0 * 576 + tap * 64;
#pragma unroll
        for (int s = 0; s < 2; ++s) {
            const int koff = (s << 5) + kqA;
            half8v a = *(const half8v*)(prow + koff);
            a = a * okh;                               // boundary zero (exact)
            half8v b0 = *(const half8v*)(wr + koff);
            half8v b1 = *(const half8v*)(wr + 16 * 576 + koff);
            cv0 = __builtin_amdgcn_mfma_f32_16x16x32_f16(a, b0, cv0, 0, 0, 0);
            cv1 = __builtin_amdgcn_mfma_f32_16x16x32_f16(a, b1, cv1, 0, 0, 0);
        }
    }

    // scatter om (verified layout: col=lane&15 -> n, row offset (lane>>4)*4+r)
    {
        const int j0 = lane & 15;
        const int pxo = (wv << 4) + ((lane >> 4) << 2);
#pragma unroll
        for (int r = 0; r < 4; ++r) {
            omb[(pxo + r) * OMS + j0] = cv0[r];
            if (j0 < 13) omb[(pxo + r) * OMS + j0 + 16] = cv1[r];
        }
    }
    __builtin_amdgcn_s_waitcnt(0xC07F);   // lgkmcnt(0): scatter visible
    __builtin_amdgcn_s_barrier();

    // ================= phase B: cooperative corner fill + packed-fp16 einsum =====
    f32x16 acc = {};
    const int mhalf = wv & 1, nhalf = wv >> 1;
    const int mrow = (mhalf << 5) + (lane & 31);
    const int nrow = (nhalf << 5) + (lane & 31);
    const int kchunk = lane >> 5;          // 0/1: which 16B chunk pair
    const int fpx0 = lane >> 3;            // fill: row-within-8
    const int fslot = lane & 7;            // fill: 16B slot
    const int dy = g >> 1, dx = g & 1;     // wave g loads corner g

#pragma unroll 1
    for (int k = 0; k < 9; ++k) {
        const int ki = k / 3, kj = k - ki * 3;
        // ---- fill: wave g loads corner (dy,dx) rows for all 64 px, full-line coop.
        // LDS dest linear in lane; bank-decollision via pre-swizzled GLOBAL chunk.
#pragma unroll
        for (int i = 0; i < 8; ++i) {
            const int p = (i << 3) + fpx0;
            const float offy = omb[p * OMS + 2 * k];
            const float offx = omb[p * OMS + 2 * k + 1];
            const float py  = (float)(h + ki - 1) + offy;
            const float pxf = (float)(wcol0 + p + kj - 1) + offx;
            const int yc = min(max((int)floorf(py)  + dy, 0), H_ - 1);
            const int xc = min(max((int)floorf(pxf) + dx, 0), W_ - 1);
            const _Float16* src = xTb + ((size_t)((yc << 7) + xc) << 6) + ((fslot ^ (p & 7)) << 3);
            load_lds16(src, &strB[(((g << 6) + (i << 3)) << 6) + (lane << 3)]);
        }

        // ---- per-lane bilinear weights for own pixel (overlaps load flight; R2 math)
        const float offy = omb[mrow * OMS + 2 * k];
        const float offx = omb[mrow * OMS + 2 * k + 1];
        const float mr   = omb[mrow * OMS + 18 + k];
        const float mk = 1.f / (1.f + __expf(-mr));
        const float py  = (float)(h + ki - 1) + offy;
        const float pxf = (float)(wcol0 + mrow + kj - 1) + offx;
        const float y0f = floorf(py), x0f = floorf(pxf);
        const int y0i = (int)y0f, x0i = (int)x0f;
        const float wy1 = py - y0f, wy0 = 1.f - wy1;
        const float wx1 = pxf - x0f, wx0 = 1.f - wx1;
        const bool vy0 = (unsigned)y0i < (unsigned)H_;
        const bool vy1 = (unsigned)(y0i + 1) < (unsigned)H_;
        const bool vx0 = (unsigned)x0i < (unsigned)W_;
        const bool vx1 = (unsigned)(x0i + 1) < (unsigned)W_;
        const float w00 = wy0 * wx0 * ((vy0 && vx0) ? mk : 0.f);
        const float w01 = wy0 * wx1 * ((vy0 && vx1) ? mk : 0.f);
        const float w10 = wy1 * wx0 * ((vy1 && vx0) ? mk : 0.f);
        const float w11 = wy1 * wx1 * ((vy1 && vx1) ? mk : 0.f);
        const _Float16 hw00 = (_Float16)w00, hw01 = (_Float16)w01;
        const _Float16 hw10 = (_Float16)w10, hw11 = (_Float16)w11;

        __builtin_amdgcn_s_waitcnt(0x0F70);   // vmcnt(0): strip loads landed
        __builtin_amdgcn_s_barrier();

        const int rsw = mrow & 7;
#pragma unroll
        for (int s = 0; s < 4; ++s) {
            const int slot = ((s << 1) + kchunk) ^ rsw;
            const _Float16* r0 = &strB[(mrow << 6) + (slot << 3)];
            half8v v00 = *(const half8v*)(r0);            // corner (y0,x0)
            half8v v01 = *(const half8v*)(r0 + 4096);     // corner (y0,x1)
            half8v v10 = *(const half8v*)(r0 + 8192);     // corner (y1,x0)
            half8v v11 = *(const half8v*)(r0 + 12288);    // corner (y1,x1)
            half8v a = v00 * hw00;                        // v_pk_mul/fma_f16 chain
            a = v01 * hw01 + a;
            a = v10 * hw10 + a;
            a = v11 * hw11 + a;
            half8v bw = *(const half8v*)&Wch2[(((((k << 2) + s) << 1) + nhalf) << 9) + (lane << 3)];
            acc = __builtin_amdgcn_mfma_f32_32x32x16_f16(a, bw, acc, 0, 0, 0);
        }
        __builtin_amdgcn_s_barrier();        // all reads done -> strip reusable
    }

    // ================= epilogue: store C (32x32 layout, verified R3) =======
    {
        float* ob = out + ((size_t)b * O_ + nrow) * HW_ + h * W_ + wcol0;
        const int rbase = ((lane >> 5) << 2) + (mhalf << 5);
#pragma unroll
        for (int q = 0; q < 4; ++q) {
            f32x4 vv = {acc[4*q], acc[4*q+1], acc[4*q+2], acc[4*q+3]};
            *(f32x4*)&ob[rbase + 8*q] = vv;
        }
    }
}

extern "C" void kernel_launch(void* const* d_in, const int* in_sizes, int n_in,
                              void* d_out, int out_size, void* d_ws, size_t ws_size,
                              hipStream_t stream) {
    const float* x      = (const float*)d_in[0];
    const float* w_conv = (const float*)d_in[1];
    const float* w_off  = (const float*)d_in[2];
    const float* w_msk  = (const float*)d_in[3];
    float* out = (float*)d_out;

    _Float16* xT   = (_Float16*)d_ws;                       // 8*16384*64 halfs = 16.78 MB
    _Float16* Wch2 = xT + (size_t)B_ * HW_ * 64;            // 9*4096 halfs
    _Float16* Womh = Wch2 + 9 * 4096;                       // 32*576 halfs

    prep_weights<<<144, 256, 0, stream>>>(w_conv, w_off, w_msk, Wch2, Womh);
    transpose_x<<<2048, 256, 0, stream>>>(x, xT);

    deform_mfma<<<2048, 256, 0, stream>>>(xT, Wch2, Womh, out);
}

// Round 7
// 178.672 us; speedup vs baseline: 2.1236x; 1.0042x over previous
//
#include <hip/hip_runtime.h>
#include <math.h>

#define B_ 8
#define C_ 64
#define H_ 128
#define W_ 128
#define O_ 64
#define HW_ (H_ * W_)
#define OMS 29     // floats per om row (odd stride -> conflict-free b32)

typedef _Float16 half8v  __attribute__((ext_vector_type(8)));
typedef float    f32x2   __attribute__((ext_vector_type(2)));
typedef float    f32x4   __attribute__((ext_vector_type(4)));
typedef float    f32x16  __attribute__((ext_vector_type(16)));

// Async global->LDS, 16B per lane, dest = uniform base + lane*16 (HW rule).
__device__ __forceinline__ void load_lds16(const void* g, void* l) {
    __builtin_amdgcn_global_load_lds((const __attribute__((address_space(1))) void*)g,
                                     (__attribute__((address_space(3))) void*)l, 16, 0, 0);
}

// ws: Wch2[9*4*2*512] f16 packed per (tap,s,nhalf) lane-blocks; Womh[32*576] f16
__global__ void prep_weights(const float* __restrict__ wc,
                             const float* __restrict__ wo,
                             const float* __restrict__ wm,
                             _Float16* __restrict__ Wch2,
                             _Float16* __restrict__ Womh)
{
    int tid = blockIdx.x * blockDim.x + threadIdx.x;
    if (tid < 9 * 4096) {   // Wch2: packed so one wave-instr reads 16 consecutive lines
        int j = tid & 7, l = (tid >> 3) & 63, nh = (tid >> 9) & 1, s = (tid >> 10) & 3, tap = tid >> 12;
        int o = nh * 32 + (l & 31);
        int c = s * 16 + ((l >> 5) << 3) + j;
        Wch2[tid] = (_Float16)wc[(o * 64 + c) * 9 + tap];
    }
    if (tid < 32 * 576) {   // Womh: [n][tap*64+c] fp16, rows >=27 zero
        int n = tid / 576, tk = tid % 576;
        int tap = tk >> 6, c = tk & 63;
        float v = 0.f;
        if (n < 18)      v = wo[(n * 64 + c) * 9 + tap];
        else if (n < 27) v = wm[((n - 18) * 64 + c) * 9 + tap];
        Womh[tid] = (_Float16)v;
    }
}

// NCHW f32 -> NHWC fp16. Pixel row = 64ch * 2B = 128B = 2 cachelines.
__global__ __launch_bounds__(256) void transpose_x(const float* __restrict__ x,
                                                   _Float16* __restrict__ xT)
{
    __shared__ float tile[64][65];
    const int t = threadIdx.x;
    const int b = blockIdx.x & 7;
    const int tp = blockIdx.x >> 3;        // 0..255: 64-pixel tile within HW
    const int lane = t & 63, wv = t >> 6;
    const float* xb = x + (size_t)b * C_ * HW_;
    const int p0 = tp * 64;
#pragma unroll
    for (int j = 0; j < 16; ++j) {
        int c = wv * 16 + j;
        tile[c][lane] = xb[(size_t)c * HW_ + p0 + lane];   // 256B coalesced
    }
    __syncthreads();
    _Float16* ob = xT + ((size_t)b * HW_ + p0) * 64;
    const int px = t >> 2, c0 = (t & 3) * 16;
    half8v h0, h1;
#pragma unroll
    for (int j = 0; j < 8; ++j) h0[j] = (_Float16)tile[c0 + j][px];
#pragma unroll
    for (int j = 0; j < 8; ++j) h1[j] = (_Float16)tile[c0 + 8 + j][px];
    *(half8v*)&ob[(size_t)px * 64 + c0] = h0;
    *(half8v*)&ob[(size_t)px * 64 + c0 + 8] = h1;
}

__global__ __launch_bounds__(256, 4) void deform_mfma(
    const _Float16* __restrict__ xT,       // NHWC fp16 (phases A and B)
    const _Float16* __restrict__ Wch2,
    const _Float16* __restrict__ Womh,
    float* __restrict__ out)
{
    __shared__ char uni[32768];            // phase B corner strip
    __shared__ float omb[64 * OMS];        // raw offset/mask conv output
    __shared__ int   pcb[576];             // packed (x0<<16)|(y0&0xffff) per (tap,px)
    __shared__ f32x2 wyb[576];             // (wy0', wy1') validity-folded
    __shared__ f32x2 wxb[576];             // (wx0'*mk, wx1'*mk) validity-folded
    _Float16* strB = (_Float16*)uni;       // [corner][px][64 halfs], 256 rows * 128B

    const int t = threadIdx.x;
    const int lane = t & 63;
    const int wv = t >> 6;
    const int g = __builtin_amdgcn_readfirstlane(wv);

    const int blk = blockIdx.x;
    const int b = blk & 7;                 // XCD-batch swizzle (verified R5)
    const int rest = blk >> 3;
    const int wcol0 = (rest & 1) << 6;
    const int h = rest >> 1;
    const _Float16* xTb = xT + (size_t)b * HW_ * 64;

    // ================= phase A: offset/mask conv, direct-from-xT fp16 MFMA ======
    f32x4 cv0 = {}, cv1 = {};
    const int mrowA = (wv << 4) + (lane & 15);   // pixel within 64-col strip
    const int kqA = (lane >> 4) << 3;            // 8-half subgroup within K=32 block
    const int n0 = lane & 15;
    const int xxA = wcol0 + mrowA - 1;
    const int yyA = h - 1;

#pragma unroll
    for (int tap = 0; tap < 9; ++tap) {
        const int ty = tap / 3, tx = tap - ty * 3;
        const int yy = yyA + ty, xx = xxA + tx;
        const bool ok = (((unsigned)yy < (unsigned)H_) && ((unsigned)xx < (unsigned)W_));
        const _Float16 okh = ok ? (_Float16)1.0f : (_Float16)0.0f;
        const int yyc = min(max(yy, 0), H_ - 1), xxc = min(max(xx, 0), W_ - 1);
        const _Float16* prow = xTb + ((size_t)((yyc << 7) + xxc) << 6);
        const _Float16* wr = Womh + n0 * 576 + tap * 64;
#pragma unroll
        for (int s = 0; s < 2; ++s) {
            const int koff = (s << 5) + kqA;
            half8v a = *(const half8v*)(prow + koff);
            a = a * okh;                               // boundary zero (exact)
            half8v b0 = *(const half8v*)(wr + koff);
            half8v b1 = *(const half8v*)(wr + 16 * 576 + koff);
            cv0 = __builtin_amdgcn_mfma_f32_16x16x32_f16(a, b0, cv0, 0, 0, 0);
            cv1 = __builtin_amdgcn_mfma_f32_16x16x32_f16(a, b1, cv1, 0, 0, 0);
        }
    }

    // scatter om (verified layout: col=lane&15 -> n, row offset (lane>>4)*4+r)
    {
        const int j0 = lane & 15;
        const int pxo = (wv << 4) + ((lane >> 4) << 2);
#pragma unroll
        for (int r = 0; r < 4; ++r) {
            omb[(pxo + r) * OMS + j0] = cv0[r];
            if (j0 < 13) omb[(pxo + r) * OMS + j0 + 16] = cv1[r];
        }
    }
    __syncthreads();   // scatter visible

    // ======= one-shot transform: omb -> pcb/wyb/wxb (separate buffers, no aliasing)
    for (int it = t; it < 576; it += 256) {
        const int p = it & 63;
        const int k = it >> 6;
        const int ki = k / 3, kj = k - ki * 3;
        const float offy = omb[p * OMS + 2 * k];
        const float offx = omb[p * OMS + 2 * k + 1];
        const float mr   = omb[p * OMS + 18 + k];
        const float mk = 1.f / (1.f + __expf(-mr));
        const float py  = (float)(h + ki - 1) + offy;
        const float pxf = (float)(wcol0 + p + kj - 1) + offx;
        const float y0f = floorf(py), x0f = floorf(pxf);
        const int y0 = (int)y0f, x0 = (int)x0f;
        const float wy1 = py - y0f, wx1 = pxf - x0f;
        const bool vy0 = (unsigned)y0 < (unsigned)H_;
        const bool vy1 = (unsigned)(y0 + 1) < (unsigned)H_;
        const bool vx0 = (unsigned)x0 < (unsigned)W_;
        const bool vx1 = (unsigned)(x0 + 1) < (unsigned)W_;
        f32x2 wy2, wx2;
        wy2[0] = vy0 ? 1.f - wy1 : 0.f;
        wy2[1] = vy1 ? wy1 : 0.f;
        wx2[0] = vx0 ? (1.f - wx1) * mk : 0.f;
        wx2[1] = vx1 ? wx1 * mk : 0.f;
        pcb[(k << 6) + p] = (x0 << 16) | (y0 & 0xffff);
        wyb[(k << 6) + p] = wy2;
        wxb[(k << 6) + p] = wx2;
    }
    __syncthreads();   // transform visible; omb dead from here

    // ================= phase B: cooperative corner fill + packed-fp16 einsum =====
    f32x16 acc = {};
    const int mhalf = wv & 1, nhalf = wv >> 1;
    const int mrow = (mhalf << 5) + (lane & 31);
    const int nrow = (nhalf << 5) + (lane & 31);
    const int kchunk = lane >> 5;          // 0/1: which 16B chunk pair
    const int fpx0 = lane >> 3;            // fill: row-within-8
    const int fslot = lane & 7;            // fill: 16B slot
    const int dy = g >> 1, dx = g & 1;     // wave g loads corner g

#pragma unroll 1
    for (int k = 0; k < 9; ++k) {
        const int kb = k << 6;
        // ---- fill: wave g loads corner (dy,dx) rows for all 64 px, full-line coop.
        // Coords precomputed once (pcb); LDS dest linear in lane (HW rule);
        // bank-decollision via pre-swizzled GLOBAL chunk.
#pragma unroll
        for (int i = 0; i < 8; ++i) {
            const int p = (i << 3) + fpx0;
            const int pc = pcb[kb + p];
            const int y0 = (pc << 16) >> 16;     // sext low half
            const int x0 = pc >> 16;             // arith high half
            const int yc = min(max(y0 + dy, 0), H_ - 1);
            const int xc = min(max(x0 + dx, 0), W_ - 1);
            const _Float16* src = xTb + ((size_t)((yc << 7) + xc) << 6) + ((fslot ^ (p & 7)) << 3);
            load_lds16(src, &strB[(((g << 6) + (i << 3)) << 6) + (lane << 3)]);
        }

        // ---- per-lane packed weights for own pixel (precomputed pairs; overlaps flight)
        const f32x2 wy = wyb[kb + mrow];
        const f32x2 wx = wxb[kb + mrow];
        const _Float16 hw00 = (_Float16)(wy[0] * wx[0]);
        const _Float16 hw01 = (_Float16)(wy[0] * wx[1]);
        const _Float16 hw10 = (_Float16)(wy[1] * wx[0]);
        const _Float16 hw11 = (_Float16)(wy[1] * wx[1]);

        __builtin_amdgcn_s_waitcnt(0x0F70);   // vmcnt(0): strip loads landed
        __builtin_amdgcn_s_barrier();

        const int rsw = mrow & 7;
#pragma unroll
        for (int s = 0; s < 4; ++s) {
            const int slot = ((s << 1) + kchunk) ^ rsw;
            const _Float16* r0 = &strB[(mrow << 6) + (slot << 3)];
            half8v v00 = *(const half8v*)(r0);            // corner (y0,x0)
            half8v v01 = *(const half8v*)(r0 + 4096);     // corner (y0,x1)
            half8v v10 = *(const half8v*)(r0 + 8192);     // corner (y1,x0)
            half8v v11 = *(const half8v*)(r0 + 12288);    // corner (y1,x1)
            half8v a = v00 * hw00;                        // v_pk_mul/fma_f16 chain
            a = v01 * hw01 + a;
            a = v10 * hw10 + a;
            a = v11 * hw11 + a;
            half8v bw = *(const half8v*)&Wch2[(((((k << 2) + s) << 1) + nhalf) << 9) + (lane << 3)];
            acc = __builtin_amdgcn_mfma_f32_32x32x16_f16(a, bw, acc, 0, 0, 0);
        }
        __builtin_amdgcn_s_barrier();        // all reads done -> strip reusable
    }

    // ================= epilogue: store C (32x32 layout, verified R3) =======
    {
        float* ob = out + ((size_t)b * O_ + nrow) * HW_ + h * W_ + wcol0;
        const int rbase = ((lane >> 5) << 2) + (mhalf << 5);
#pragma unroll
        for (int q = 0; q < 4; ++q) {
            f32x4 vv = {acc[4*q], acc[4*q+1], acc[4*q+2], acc[4*q+3]};
            *(f32x4*)&ob[rbase + 8*q] = vv;
        }
    }
}

extern "C" void kernel_launch(void* const* d_in, const int* in_sizes, int n_in,
                              void* d_out, int out_size, void* d_ws, size_t ws_size,
                              hipStream_t stream) {
    const float* x      = (const float*)d_in[0];
    const float* w_conv = (const float*)d_in[1];
    const float* w_off  = (const float*)d_in[2];
    const float* w_msk  = (const float*)d_in[3];
    float* out = (float*)d_out;

    _Float16* xT   = (_Float16*)d_ws;                       // 8*16384*64 halfs = 16.78 MB
    _Float16* Wch2 = xT + (size_t)B_ * HW_ * 64;            // 9*4096 halfs
    _Float16* Womh = Wch2 + 9 * 4096;                       // 32*576 halfs

    prep_weights<<<144, 256, 0, stream>>>(w_conv, w_off, w_msk, Wch2, Womh);
    transpose_x<<<2048, 256, 0, stream>>>(x, xT);

    deform_mfma<<<2048, 256, 0, stream>>>(xT, Wch2, Womh, out);
}

// Round 9
// 174.183 us; speedup vs baseline: 2.1784x; 1.0258x over previous
//
#include <hip/hip_runtime.h>
#include <math.h>

#define B_ 8
#define C_ 64
#define H_ 128
#define W_ 128
#define O_ 64
#define HW_ (H_ * W_)
#define OMS 27     // floats per om row (odd stride -> conflict-free b32); 27 channels exactly

typedef _Float16 half8v  __attribute__((ext_vector_type(8)));
typedef float    f32x4   __attribute__((ext_vector_type(4)));
typedef float    f32x16  __attribute__((ext_vector_type(16)));

// Async global->LDS, 16B per lane, dest = uniform base + lane*16 (HW rule).
__device__ __forceinline__ void load_lds16(const void* g, void* l) {
    __builtin_amdgcn_global_load_lds((const __attribute__((address_space(1))) void*)g,
                                     (__attribute__((address_space(3))) void*)l, 16, 0, 0);
}

// ws: Wch2[9*4*2*512] f16 packed per (tap,s,nhalf) lane-blocks; Womh[32*576] f16
__global__ void prep_weights(const float* __restrict__ wc,
                             const float* __restrict__ wo,
                             const float* __restrict__ wm,
                             _Float16* __restrict__ Wch2,
                             _Float16* __restrict__ Womh)
{
    int tid = blockIdx.x * blockDim.x + threadIdx.x;
    if (tid < 9 * 4096) {   // Wch2: packed so one wave-instr reads 16 consecutive lines
        int j = tid & 7, l = (tid >> 3) & 63, nh = (tid >> 9) & 1, s = (tid >> 10) & 3, tap = tid >> 12;
        int o = nh * 32 + (l & 31);
        int c = s * 16 + ((l >> 5) << 3) + j;
        Wch2[tid] = (_Float16)wc[(o * 64 + c) * 9 + tap];
    }
    if (tid < 32 * 576) {   // Womh: [n][tap*64+c] fp16, rows >=27 zero
        int n = tid / 576, tk = tid % 576;
        int tap = tk >> 6, c = tk & 63;
        float v = 0.f;
        if (n < 18)      v = wo[(n * 64 + c) * 9 + tap];
        else if (n < 27) v = wm[((n - 18) * 64 + c) * 9 + tap];
        Womh[tid] = (_Float16)v;
    }
}

// NCHW f32 -> NHWC fp16. Pixel row = 64ch * 2B = 128B = 2 cachelines.
__global__ __launch_bounds__(256) void transpose_x(const float* __restrict__ x,
                                                   _Float16* __restrict__ xT)
{
    __shared__ float tile[64][65];
    const int t = threadIdx.x;
    const int b = blockIdx.x & 7;
    const int tp = blockIdx.x >> 3;        // 0..255: 64-pixel tile within HW
    const int lane = t & 63, wv = t >> 6;
    const float* xb = x + (size_t)b * C_ * HW_;
    const int p0 = tp * 64;
#pragma unroll
    for (int j = 0; j < 16; ++j) {
        int c = wv * 16 + j;
        tile[c][lane] = xb[(size_t)c * HW_ + p0 + lane];   // 256B coalesced
    }
    __syncthreads();
    _Float16* ob = xT + ((size_t)b * HW_ + p0) * 64;
    const int px = t >> 2, c0 = (t & 3) * 16;
    half8v h0, h1;
#pragma unroll
    for (int j = 0; j < 8; ++j) h0[j] = (_Float16)tile[c0 + j][px];
#pragma unroll
    for (int j = 0; j < 8; ++j) h1[j] = (_Float16)tile[c0 + 8 + j][px];
    *(half8v*)&ob[(size_t)px * 64 + c0] = h0;
    *(half8v*)&ob[(size_t)px * 64 + c0 + 8] = h1;
}

__global__ __launch_bounds__(256, 4) void deform_mfma(
    const _Float16* __restrict__ xT,       // NHWC fp16 (phases A and B)
    const _Float16* __restrict__ Wch2,
    const _Float16* __restrict__ Womh,
    float* __restrict__ out)
{
    __shared__ char uni[32768];            // phase B corner strip
    __shared__ float omb[64 * OMS];        // raw offset/mask conv output (6912 B)
    __shared__ unsigned short pcbu[576];   // biased u8 coord pairs (x0+16)<<8|(y0+16) (1152 B)
    _Float16* strB = (_Float16*)uni;       // [corner][px][64 halfs], 256 rows * 128B
    // total 40832 B -> 40960 block -> 4 blocks/CU (back from R7's 3)

    const int t = threadIdx.x;
    const int lane = t & 63;
    const int wv = t >> 6;
    const int g = __builtin_amdgcn_readfirstlane(wv);

    const int blk = blockIdx.x;
    const int b = blk & 7;                 // XCD-batch swizzle (verified R5)
    const int rest = blk >> 3;
    const int wcol0 = (rest & 1) << 6;
    const int h = rest >> 1;
    const _Float16* xTb = xT + (size_t)b * HW_ * 64;

    // ================= phase A: offset/mask conv, direct-from-xT fp16 MFMA ======
    f32x4 cv0 = {}, cv1 = {};
    const int mrowA = (wv << 4) + (lane & 15);   // pixel within 64-col strip
    const int kqA = (lane >> 4) << 3;            // 8-half subgroup within K=32 block
    const int n0 = lane & 15;
    const int xxA = wcol0 + mrowA - 1;
    const int yyA = h - 1;

#pragma unroll
    for (int tap = 0; tap < 9; ++tap) {
        const int ty = tap / 3, tx = tap - ty * 3;
        const int yy = yyA + ty, xx = xxA + tx;
        const bool ok = (((unsigned)yy < (unsigned)H_) && ((unsigned)xx < (unsigned)W_));
        const _Float16 okh = ok ? (_Float16)1.0f : (_Float16)0.0f;
        const int yyc = min(max(yy, 0), H_ - 1), xxc = min(max(xx, 0), W_ - 1);
        const _Float16* prow = xTb + ((size_t)((yyc << 7) + xxc) << 6);
        const _Float16* wr = Womh + n0 * 576 + tap * 64;
#pragma unroll
        for (int s = 0; s < 2; ++s) {
            const int koff = (s << 5) + kqA;
            half8v a = *(const half8v*)(prow + koff);
            a = a * okh;                               // boundary zero (exact)
            half8v b0 = *(const half8v*)(wr + koff);
            half8v b1 = *(const half8v*)(wr + 16 * 576 + koff);
            cv0 = __builtin_amdgcn_mfma_f32_16x16x32_f16(a, b0, cv0, 0, 0, 0);
            cv1 = __builtin_amdgcn_mfma_f32_16x16x32_f16(a, b1, cv1, 0, 0, 0);
        }
    }

    // scatter om (verified layout; OMS=27 -> only channels 16..26 from cv1: j0<11)
    {
        const int j0 = lane & 15;
        const int pxo = (wv << 4) + ((lane >> 4) << 2);
#pragma unroll
        for (int r = 0; r < 4; ++r) {
            omb[(pxo + r) * OMS + j0] = cv0[r];
            if (j0 < 11) omb[(pxo + r) * OMS + j0 + 16] = cv1[r];
        }
    }
    __syncthreads();   // scatter visible

    // ======= per-lane transform (R7 math, buffers shrunk):
    //   lane l computes pixel l's coords -> pcbu (wave 0 stores; values stable all phase B)
    //   lane computes pixel mrow's fused fp16 weights -> REGISTERS hw[9][4]
    const int mhalf = wv & 1, nhalf = wv >> 1;
    const int mrow = (mhalf << 5) + (lane & 31);
    _Float16 hw[9][4];
    {
#pragma unroll
        for (int k = 0; k < 9; ++k) {
            const int ki = k / 3, kj = k - ki * 3;     // compile-time (unrolled)
            // coords for pixel `lane`
            const float offyc = omb[lane * OMS + 2 * k];
            const float offxc = omb[lane * OMS + 2 * k + 1];
            const float pyc = (float)(h + ki - 1) + offyc;
            const float pxc = (float)(wcol0 + lane + kj - 1) + offxc;
            const int y0c = min(max((int)floorf(pyc), -16), 199) + 16;   // bias to u8
            const int x0c = min(max((int)floorf(pxc), -16), 199) + 16;
            if (wv == 0) pcbu[(k << 6) + lane] = (unsigned short)((x0c << 8) | y0c);
            // weights for pixel `mrow` (same association as R7 -> bit-identical)
            const float offy = omb[mrow * OMS + 2 * k];
            const float offx = omb[mrow * OMS + 2 * k + 1];
            const float mr   = omb[mrow * OMS + 18 + k];
            const float mk = 1.f / (1.f + __expf(-mr));
            const float py  = (float)(h + ki - 1) + offy;
            const float pxf = (float)(wcol0 + mrow + kj - 1) + offx;
            const float y0f = floorf(py), x0f = floorf(pxf);
            const int y0 = (int)y0f, x0 = (int)x0f;
            const float wy1 = py - y0f, wx1 = pxf - x0f;
            const bool vy0 = (unsigned)y0 < (unsigned)H_;
            const bool vy1 = (unsigned)(y0 + 1) < (unsigned)H_;
            const bool vx0 = (unsigned)x0 < (unsigned)W_;
            const bool vx1 = (unsigned)(x0 + 1) < (unsigned)W_;
            const float wy0v = vy0 ? 1.f - wy1 : 0.f;
            const float wy1v = vy1 ? wy1 : 0.f;
            const float wx0v = vx0 ? (1.f - wx1) * mk : 0.f;
            const float wx1v = vx1 ? wx1 * mk : 0.f;
            hw[k][0] = (_Float16)(wy0v * wx0v);
            hw[k][1] = (_Float16)(wy0v * wx1v);
            hw[k][2] = (_Float16)(wy1v * wx0v);
            hw[k][3] = (_Float16)(wy1v * wx1v);
        }
    }
    __syncthreads();   // pcbu visible; omb stays valid (unused) -- strB is separate

    // ================= phase B: cooperative corner fill + packed-fp16 einsum =====
    // Fully unrolled over taps so hw[k][*] stays in registers (rule #20).
    f32x16 acc = {};
    const int kchunk = lane >> 5;          // 0/1: which 16B chunk pair
    const int fpx0 = lane >> 3;            // fill: row-within-8
    const int fslot = lane & 7;            // fill: 16B slot
    const int srcsl = (fslot ^ fpx0) << 3; // hoisted: (p&7)==fpx0 for p=(i<<3)+fpx0
    const int dy = g >> 1, dx = g & 1;     // wave g loads corner g
    const int rsw = mrow & 7;

#pragma unroll
    for (int k = 0; k < 9; ++k) {
        const int kb = k << 6;
        // ---- fill: wave g loads corner (dy,dx) rows for all 64 px, full-line coop.
#pragma unroll
        for (int i = 0; i < 8; ++i) {
            const int p = (i << 3) + fpx0;
            const unsigned pc = pcbu[kb + p];
            const int y0 = (int)(pc & 0xFFu) - 16;
            const int x0 = (int)(pc >> 8) - 16;
            const int yc = min(max(y0 + dy, 0), H_ - 1);
            const int xc = min(max(x0 + dx, 0), W_ - 1);
            const _Float16* src = xTb + ((size_t)((yc << 7) + xc) << 6) + srcsl;
            load_lds16(src, &strB[(((g << 6) + (i << 3)) << 6) + (lane << 3)]);
        }

        __builtin_amdgcn_s_waitcnt(0x0F70);   // vmcnt(0): strip loads landed
        __builtin_amdgcn_s_barrier();

#pragma unroll
        for (int s = 0; s < 4; ++s) {
            const int slot = ((s << 1) + kchunk) ^ rsw;
            const _Float16* r0 = &strB[(mrow << 6) + (slot << 3)];
            half8v v00 = *(const half8v*)(r0);            // corner (y0,x0)
            half8v v01 = *(const half8v*)(r0 + 4096);     // corner (y0,x1)
            half8v v10 = *(const half8v*)(r0 + 8192);     // corner (y1,x0)
            half8v v11 = *(const half8v*)(r0 + 12288);    // corner (y1,x1)
            half8v a = v00 * hw[k][0];                    // v_pk_mul/fma_f16 chain
            a = v01 * hw[k][1] + a;
            a = v10 * hw[k][2] + a;
            a = v11 * hw[k][3] + a;
            half8v bw = *(const half8v*)&Wch2[(((((k << 2) + s) << 1) + nhalf) << 9) + (lane << 3)];
            acc = __builtin_amdgcn_mfma_f32_32x32x16_f16(a, bw, acc, 0, 0, 0);
        }
        __builtin_amdgcn_s_barrier();        // all reads done -> strip reusable
    }

    // ================= epilogue: store C (32x32 layout, verified R3) =======
    {
        const int nrow = (nhalf << 5) + (lane & 31);
        float* ob = out + ((size_t)b * O_ + nrow) * HW_ + h * W_ + wcol0;
        const int rbase = ((lane >> 5) << 2) + (mhalf << 5);
#pragma unroll
        for (int q = 0; q < 4; ++q) {
            f32x4 vv = {acc[4*q], acc[4*q+1], acc[4*q+2], acc[4*q+3]};
            *(f32x4*)&ob[rbase + 8*q] = vv;
        }
    }
}

extern "C" void kernel_launch(void* const* d_in, const int* in_sizes, int n_in,
                              void* d_out, int out_size, void* d_ws, size_t ws_size,
                              hipStream_t stream) {
    const float* x      = (const float*)d_in[0];
    const float* w_conv = (const float*)d_in[1];
    const float* w_off  = (const float*)d_in[2];
    const float* w_msk  = (const float*)d_in[3];
    float* out = (float*)d_out;

    _Float16* xT   = (_Float16*)d_ws;                       // 8*16384*64 halfs = 16.78 MB
    _Float16* Wch2 = xT + (size_t)B_ * HW_ * 64;            // 9*4096 halfs
    _Float16* Womh = Wch2 + 9 * 4096;                       // 32*576 halfs

    prep_weights<<<144, 256, 0, stream>>>(w_conv, w_off, w_msk, Wch2, Womh);
    transpose_x<<<2048, 256, 0, stream>>>(x, xT);

    deform_mfma<<<2048, 256, 0, stream>>>(xT, Wch2, Womh, out);
}